// Round 2
// baseline (245.190 us; speedup 1.0000x reference)
//
#include <hip/hip_runtime.h>

#define TB 512
#define TF 1280
#define TH 2560
#define TK 8
#define TE 9

typedef unsigned short ushortT;
typedef __attribute__((ext_vector_type(8))) short short8;
typedef __attribute__((ext_vector_type(4))) float floatx4;

__device__ __forceinline__ unsigned short f2bf(float f) {
  union { float f; unsigned u; } v; v.f = f;
  unsigned r = v.u + 0x7fffu + ((v.u >> 16) & 1u);   // RNE
  return (unsigned short)(r >> 16);
}

// pack two fp32 -> (bf16(a) low, bf16(b) high), RNE, via v_perm
__device__ __forceinline__ unsigned pk2(float a, float b) {
  union { float f; unsigned u; } ua, ub; ua.f = a; ub.f = b;
  unsigned ra = ua.u + 0x7fffu + ((ua.u >> 16) & 1u);
  unsigned rb = ub.u + 0x7fffu + ((ub.u >> 16) & 1u);
  return __builtin_amdgcn_perm(rb, ra, 0x07060302);  // {ra[31:16], rb[31:16]}
}

__device__ __forceinline__ void gl_lds16(const void* g, void* l) {
  __builtin_amdgcn_global_load_lds(
      (const __attribute__((address_space(1))) unsigned*)g,
      (__attribute__((address_space(3))) unsigned*)l, 16, 0, 0);
}

// ---------------- prepass: x -> bf16, W2 -> bf16 transposed [e][n][h] -------
__global__ __launch_bounds__(256) void prepass(
    const float* __restrict__ x, const float* __restrict__ W2,
    ushortT* __restrict__ xb, ushortT* __restrict__ W2t) {
  const int i = blockIdx.x * 256 + threadIdx.x;
  if (i < TB * TF / 2) {                      // 327680 float2 pairs of x
    float2 v = ((const float2*)x)[i];
    ((unsigned*)xb)[i] = pk2(v.x, v.y);
  } else {
    const int o = i - TB * TF / 2;
    if (o < TE * TK * TH) {                   // 184320 elements of W2t
      const int hcol = o % TH;
      const int rest = o / TH;
      const int n = rest & 7;
      const int e = rest >> 3;
      W2t[(long)(e * TK + n) * TH + hcol] = f2bf(W2[((long)e * TH + hcol) * TK + n]);
    }
  }
}

// ---------------- gemm1: h = relu(x @ W1 + b1), bf16 out --------------------
// BM=128 BN=128 BK=64; 256 thr = 4 waves (2x2), 4x4 frags of 16x16x32.
// A: bf16 x staged via global_load_lds (chunk-swizzled, conflict-free reads).
// B: fp32 W1 strided float4 loads, register-prefetched across the barrier,
//    RNE-packed to bf16, ds_write_b64 into ld=72 LDS.
__global__ __launch_bounds__(256, 3) void gemm1_relu(
    const ushortT* __restrict__ xb, const float* __restrict__ W1,
    const float* __restrict__ b1, ushortT* __restrict__ h) {
  __shared__ __align__(16) ushortT As[128 * 64];   // swizzled chunks, 16 KB
  __shared__ __align__(16) ushortT Bs[128 * 72];   // [n][k] ld=72, 18 KB

  const int t = threadIdx.x;
  const int tileN = blockIdx.x;          // 0..179
  const int e = tileN / 20;
  const int hbase = (tileN % 20) * 128;
  const int m0 = blockIdx.y * 128;

  const int lane = t & 63, w = t >> 6;
  const int wm = w & 1, wn = w >> 1;
  const int lm = lane & 15, lq = lane >> 4;

  // B staging mapping: lanes vary over k (coalesce-ok), 4-way-max LDS writes
  const int kk4 = (t & 15) * 4;          // k quad base 0..60
  const int n0 = (t >> 4) * 8;           // n group 0..120

  floatx4 acc[4][4];
#pragma unroll
  for (int i = 0; i < 4; ++i)
#pragma unroll
    for (int j = 0; j < 4; ++j) acc[i][j] = (floatx4){0.f, 0.f, 0.f, 0.f};

  const float* wbase = W1 + ((long)e * TF) * TH + hbase + n0;

  floatx4 bv[4][2];
  // prologue prefetch kt=0
#pragma unroll
  for (int r = 0; r < 4; ++r)
#pragma unroll
    for (int c = 0; c < 2; ++c)
      bv[r][c] = *(const floatx4*)(wbase + (long)(kk4 + r) * TH + c * 4);

  for (int kt = 0; kt < TF / 64; ++kt) {
    const int k0 = kt * 64;
    if (kt) __syncthreads();             // barrier A: LDS free to overwrite

    // A: 4x global_load_lds_dwordx4, chunk slot s holds (m=s>>3, c=(s&7)^(m&7))
#pragma unroll
    for (int j = 0; j < 4; ++j) {
      const int s = j * 256 + w * 64 + lane;
      const int m = s >> 3;
      const int cc = (s & 7) ^ (m & 7);
      const ushortT* src = xb + (long)(m0 + m) * TF + k0 + cc * 8;
      gl_lds16(src, (void*)&As[(j * 256 + w * 64) * 8]);
    }
    // B: convert prefetched regs, write transposed b64s
#pragma unroll
    for (int j = 0; j < 8; ++j) {
      const int c = j >> 2, q = j & 3;
      unsigned w0 = pk2(bv[0][c][q], bv[1][c][q]);
      unsigned w1 = pk2(bv[2][c][q], bv[3][c][q]);
      unsigned long long p = (unsigned long long)w0 | ((unsigned long long)w1 << 32);
      *(unsigned long long*)&Bs[(n0 + j) * 72 + kk4] = p;
    }
    __syncthreads();                     // barrier B: staging visible

    // prefetch next kt's B (lands during MFMA phase)
    if (kt + 1 < TF / 64) {
#pragma unroll
      for (int r = 0; r < 4; ++r)
#pragma unroll
        for (int c = 0; c < 2; ++c)
          bv[r][c] = *(const floatx4*)(wbase + (long)(k0 + 64 + kk4 + r) * TH + c * 4);
    }

#pragma unroll
    for (int kk = 0; kk < 2; ++kk) {
      short8 af[4], bf[4];
#pragma unroll
      for (int mg = 0; mg < 4; ++mg) {
        const int m = wm * 64 + mg * 16 + lm;
        const int swz = (kk * 4 + lq) ^ (m & 7);
        af[mg] = *(const short8*)&As[m * 64 + swz * 8];
      }
#pragma unroll
      for (int ng = 0; ng < 4; ++ng) {
        const int n = wn * 64 + ng * 16 + lm;
        bf[ng] = *(const short8*)&Bs[n * 72 + kk * 32 + lq * 8];
      }
#pragma unroll
      for (int mg = 0; mg < 4; ++mg)
#pragma unroll
        for (int ng = 0; ng < 4; ++ng)
          acc[mg][ng] = __builtin_amdgcn_mfma_f32_16x16x32_bf16(af[mg], bf[ng], acc[mg][ng], 0, 0, 0);
    }
  }

  // epilogue: C/D layout col=lane&15, row=(lane>>4)*4+reg
#pragma unroll
  for (int mg = 0; mg < 4; ++mg) {
    const int row = m0 + wm * 64 + mg * 16 + lq * 4;
#pragma unroll
    for (int ng = 0; ng < 4; ++ng) {
      const int col = hbase + wn * 64 + ng * 16 + lm;
      const float bias = b1[e * TH + col];
      floatx4 c = acc[mg][ng];
#pragma unroll
      for (int r = 0; r < 4; ++r) {
        float v = c[r] + bias;
        v = v > 0.f ? v : 0.f;
        h[((long)e * TB + row + r) * TH + col] = f2bf(v);
      }
    }
  }
}

// ---------------- gemm2 + softmax: 288 blocks, K-split across 4 waves -------
__global__ __launch_bounds__(256) void gemm2_softmax(
    const ushortT* __restrict__ h, const ushortT* __restrict__ W2t,
    const float* __restrict__ b2, float* __restrict__ logits_out,
    float* __restrict__ probs) {
  __shared__ float Ls[4][16][8];
  const int t = threadIdx.x;
  const int lane = t & 63, w = t >> 6;
  const int e = blockIdx.x >> 5;          // 9 experts x 32 row-tiles
  const int r0 = (blockIdx.x & 31) * 16;
  const int lm = lane & 15, lq = lane >> 4;

  const ushortT* hp = h + ((long)(e * TB + r0 + lm)) * TH + w * 640 + lq * 8;
  const int bn = lm < 8 ? lm : 7;        // clamp; cols 8..15 are garbage/unused
  const ushortT* wp = W2t + ((long)(e * TK + bn)) * TH + w * 640 + lq * 8;

  floatx4 acc = (floatx4){0.f, 0.f, 0.f, 0.f};
#pragma unroll
  for (int kt = 0; kt < 20; ++kt) {
    short8 a = *(const short8*)(hp + kt * 32);
    short8 b = *(const short8*)(wp + kt * 32);
    acc = __builtin_amdgcn_mfma_f32_16x16x32_bf16(a, b, acc, 0, 0, 0);
  }
  if (lm < 8) {
#pragma unroll
    for (int r = 0; r < 4; ++r) Ls[w][lq * 4 + r][lm] = acc[r];
  }
  __syncthreads();
  if (w == 0 && lm < 8) {
    const float bias = b2[e * TK + lm];
#pragma unroll
    for (int r = 0; r < 4; ++r) {
      const int row = lq * 4 + r;
      float v = Ls[0][row][lm] + Ls[1][row][lm] + Ls[2][row][lm] + Ls[3][row][lm] + bias;
      float mx = v;
      mx = fmaxf(mx, __shfl_xor(mx, 1, 64));
      mx = fmaxf(mx, __shfl_xor(mx, 2, 64));
      mx = fmaxf(mx, __shfl_xor(mx, 4, 64));
      float ex = __expf(v - mx);
      float sm = ex;
      sm += __shfl_xor(sm, 1, 64);
      sm += __shfl_xor(sm, 2, 64);
      sm += __shfl_xor(sm, 4, 64);
      const long idx = ((long)e * TB + r0 + row) * TK + lm;
      logits_out[idx] = v;
      probs[idx] = ex / sm;
    }
  }
}

// ---------------- leaf path products ----------------------------------------
__global__ __launch_bounds__(256) void leafk(const float* __restrict__ probs,
                                             float* __restrict__ out) {
  const int idx = blockIdx.x * 256 + threadIdx.x;
  if (idx >= TB * 73) return;
  const int b = idx / 73, c = idx % 73;
  float v;
  if (c == 0) {
    v = 1.0f;
  } else if (c < 9) {
    v = probs[(long)b * TK + (c - 1)];
  } else {
    const int i = (c - 9) >> 3, j = (c - 9) & 7;
    v = probs[(long)b * TK + i] * probs[((long)(1 + i) * TB + b) * TK + j];
  }
  out[idx] = v;
}

extern "C" void kernel_launch(void* const* d_in, const int* in_sizes, int n_in,
                              void* d_out, int out_size, void* d_ws, size_t ws_size,
                              hipStream_t stream) {
  const float* x  = (const float*)d_in[0];
  const float* W1 = (const float*)d_in[1];
  const float* b1 = (const float*)d_in[2];
  const float* W2 = (const float*)d_in[3];
  const float* b2 = (const float*)d_in[4];
  float* out = (float*)d_out;

  // ws layout
  ushortT* h      = (ushortT*)d_ws;                                     // 23,592,960 B
  float*   probs  = (float*)((char*)d_ws + 23592960);                   //    147,456 B
  ushortT* xb     = (ushortT*)((char*)d_ws + 23740416);                 //  1,310,720 B
  ushortT* W2t    = (ushortT*)((char*)d_ws + 25051136);                 //    368,640 B
  float* logits_out = out + TB * 73;

  prepass<<<2000, 256, 0, stream>>>(x, W2, xb, W2t);
  gemm1_relu<<<dim3(180, 4), 256, 0, stream>>>(xb, W1, b1, h);
  gemm2_softmax<<<TE * 32, 256, 0, stream>>>(h, W2t, b2, logits_out, probs);
  leafk<<<(TB * 73 + 255) / 256, 256, 0, stream>>>(probs, out);
}